// Round 1
// baseline (5206.855 us; speedup 1.0000x reference)
//
#include <hip/hip_runtime.h>

#define N_NODES 100000
#define N_EDGES 1600000
#define D 64

// ---------------- degree count + inversion ----------------
__global__ void count_kernel(const int* __restrict__ dst, float* __restrict__ cnt) {
    int e = blockIdx.x * blockDim.x + threadIdx.x;
    if (e < N_EDGES) atomicAdd(&cnt[dst[e]], 1.0f);
}

__global__ void inv_kernel(float* __restrict__ cnt) {
    int n = blockIdx.x * blockDim.x + threadIdx.x;
    if (n < N_NODES) cnt[n] = 1.0f / fmaxf(cnt[n], 1.0f);
}

// ---------------- edge scatter-add: agg[dst] += h[src] ----------------
// 16 threads per edge, each handles 4 consecutive features (float4 gather + 4 atomics)
__global__ void scatter_kernel(const float* __restrict__ h,
                               const int* __restrict__ src,
                               const int* __restrict__ dst,
                               float* __restrict__ agg) {
    long long gid = (long long)blockIdx.x * blockDim.x + threadIdx.x;
    int e = (int)(gid >> 4);
    if (e >= N_EDGES) return;
    int part = (int)(gid & 15);

    int s = src[e];
    int d = dst[e];
    float4 v = *reinterpret_cast<const float4*>(&h[(long long)s * D + part * 4]);
    float* a = &agg[(long long)d * D + part * 4];
    atomicAdd(a + 0, v.x);
    atomicAdd(a + 1, v.y);
    atomicAdd(a + 2, v.z);
    atomicAdd(a + 3, v.w);
}

// ---------------- dense: out = (agg*inv) @ Wl^T + h @ Wr^T + b, optional ReLU ----------------
// 256 threads = 4 waves; wave nl handles node (base+nl), lane = output channel o.
// Weights staged transposed [k][o]: lane-consecutive -> conflict-free; row values
// smean[nl][k] are wave-uniform -> LDS broadcast (free).
__global__ __launch_bounds__(256) void dense_kernel(
    const float* __restrict__ agg, const float* __restrict__ inv,
    const float* __restrict__ hin,
    const float* __restrict__ Wl, const float* __restrict__ Wr,
    const float* __restrict__ bvec, float* __restrict__ out, int relu)
{
    __shared__ float WlT[D * D];
    __shared__ float WrT[D * D];
    __shared__ float bias[D];
    __shared__ float smean[4][D];
    __shared__ float sh[4][D];

    int t = threadIdx.x;
    for (int i = t; i < D * D; i += 256) {
        int o = i >> 6, k = i & 63;
        WlT[k * D + o] = Wl[i];
        WrT[k * D + o] = Wr[i];
    }
    if (t < D) bias[t] = bvec[t];
    __syncthreads();

    int nl = t >> 6;   // wave id 0..3
    int o  = t & 63;   // lane = output channel

    for (int base = blockIdx.x * 4; base < N_NODES; base += gridDim.x * 4) {
        int node = base + nl;
        float m = 0.f, hv = 0.f;
        if (node < N_NODES) {
            m  = agg[(long long)node * D + o] * inv[node];
            hv = hin[(long long)node * D + o];
        }
        smean[nl][o] = m;
        sh[nl][o]    = hv;
        __syncthreads();
        if (node < N_NODES) {
            float acc = bias[o];
            #pragma unroll
            for (int k = 0; k < D; ++k) {
                acc += smean[nl][k] * WlT[k * D + o] + sh[nl][k] * WrT[k * D + o];
            }
            if (relu) acc = fmaxf(acc, 0.f);
            out[(long long)node * D + o] = acc;
        }
        __syncthreads();
    }
}

extern "C" void kernel_launch(void* const* d_in, const int* in_sizes, int n_in,
                              void* d_out, int out_size, void* d_ws, size_t ws_size,
                              hipStream_t stream) {
    const float* x   = (const float*)d_in[0];
    const int*   ei  = (const int*)d_in[1];
    const int*   src = ei;
    const int*   dst = ei + N_EDGES;
    const float* Wl0 = (const float*)d_in[2];
    const float* Wr0 = (const float*)d_in[3];
    const float* b0  = (const float*)d_in[4];
    const float* Wl1 = (const float*)d_in[5];
    const float* Wr1 = (const float*)d_in[6];
    const float* b1  = (const float*)d_in[7];
    const float* Wl2 = (const float*)d_in[8];
    const float* Wr2 = (const float*)d_in[9];
    const float* b2  = (const float*)d_in[10];
    float* out = (float*)d_out;

    float* inv = (float*)d_ws;                    // N floats
    float* agg = inv + N_NODES;                   // N*D floats
    float* h0  = agg + (size_t)N_NODES * D;       // N*D floats
    float* h1  = h0  + (size_t)N_NODES * D;       // N*D floats

    const int BLK = 256;
    const int cnt_grid   = (N_EDGES + BLK - 1) / BLK;
    const int inv_grid   = (N_NODES + BLK - 1) / BLK;
    const int scat_grid  = (int)(((long long)N_EDGES * 16 + BLK - 1) / BLK);
    const int dense_grid = (N_NODES + 3) / 4;

    // degree counts (graph-only, computed once per call)
    hipMemsetAsync(inv, 0, (size_t)N_NODES * sizeof(float), stream);
    count_kernel<<<cnt_grid, BLK, 0, stream>>>(dst, inv);
    inv_kernel<<<inv_grid, BLK, 0, stream>>>(inv);

    // layer 0
    hipMemsetAsync(agg, 0, (size_t)N_NODES * D * sizeof(float), stream);
    scatter_kernel<<<scat_grid, BLK, 0, stream>>>(x, src, dst, agg);
    dense_kernel<<<dense_grid, BLK, 0, stream>>>(agg, inv, x, Wl0, Wr0, b0, h0, 1);

    // layer 1
    hipMemsetAsync(agg, 0, (size_t)N_NODES * D * sizeof(float), stream);
    scatter_kernel<<<scat_grid, BLK, 0, stream>>>(h0, src, dst, agg);
    dense_kernel<<<dense_grid, BLK, 0, stream>>>(agg, inv, h0, Wl1, Wr1, b1, h1, 1);

    // layer 2 (no ReLU)
    hipMemsetAsync(agg, 0, (size_t)N_NODES * D * sizeof(float), stream);
    scatter_kernel<<<scat_grid, BLK, 0, stream>>>(h1, src, dst, agg);
    dense_kernel<<<dense_grid, BLK, 0, stream>>>(agg, inv, h1, Wl2, Wr2, b2, out, 0);
}

// Round 2
// 657.990 us; speedup vs baseline: 7.9133x; 7.9133x over previous
//
#include <hip/hip_runtime.h>

#define N_NODES 100000
#define N_EDGES 1600000
#define D 64
#define SCAN_BLK 1024

// ---------------- degree count (int atomics) ----------------
__global__ void count_kernel(const int* __restrict__ dst, int* __restrict__ cnt) {
    int e = blockIdx.x * blockDim.x + threadIdx.x;
    if (e < N_EDGES) atomicAdd(&cnt[dst[e]], 1);
}

// ---------------- exclusive scan of cnt -> row_ptr ----------------
// Brute-force hierarchical: each block sums all elements before its chunk
// (98 blocks x <=100k strided loads = ~5M reads, trivial), then LDS
// Hillis-Steele scan of its own 1024-chunk.
__global__ __launch_bounds__(SCAN_BLK) void scan_kernel(const int* __restrict__ cnt,
                                                        int* __restrict__ row_ptr) {
    __shared__ int s[SCAN_BLK];
    __shared__ int red[SCAN_BLK / 64];
    int t = threadIdx.x;
    long long blockStart = (long long)blockIdx.x * SCAN_BLK;

    // global offset = sum cnt[0 .. blockStart)
    int partial = 0;
    for (long long i = t; i < blockStart; i += SCAN_BLK) partial += cnt[i];
    for (int off = 32; off > 0; off >>= 1) partial += __shfl_down(partial, off, 64);
    if ((t & 63) == 0) red[t >> 6] = partial;
    __syncthreads();
    if (t == 0) {
        int a = 0;
        for (int w = 0; w < SCAN_BLK / 64; ++w) a += red[w];
        red[0] = a;
    }
    __syncthreads();
    int offset = red[0];

    int idx = (int)blockStart + t;
    int v = (idx < N_NODES) ? cnt[idx] : 0;
    s[t] = v;
    __syncthreads();
    for (int off = 1; off < SCAN_BLK; off <<= 1) {
        int a = (t >= off) ? s[t - off] : 0;
        __syncthreads();
        s[t] += a;
        __syncthreads();
    }
    if (idx < N_NODES) row_ptr[idx] = offset + s[t] - v;  // exclusive
}

// ---------------- CSR bucket fill ----------------
__global__ void fill_kernel(const int* __restrict__ src, const int* __restrict__ dst,
                            const int* __restrict__ row_ptr, int* __restrict__ cur,
                            int* __restrict__ csr_src) {
    int e = blockIdx.x * blockDim.x + threadIdx.x;
    if (e < N_EDGES) {
        int d = dst[e];
        int pos = row_ptr[d] + atomicAdd(&cur[d], 1);
        csr_src[pos] = src[e];
    }
}

__global__ void inv_kernel(const int* __restrict__ cnt, float* __restrict__ inv) {
    int n = blockIdx.x * blockDim.x + threadIdx.x;
    if (n < N_NODES) inv[n] = 1.0f / fmaxf((float)cnt[n], 1.0f);
}

// ---------------- fused SAGE layer: gather-mean + dual matmul + bias (+ReLU) ----------------
// 256 threads = 4 waves; wave nl = one node, lane o = channel.
// Neighbor sum accumulates in a register (per edge: one coalesced 256B row read).
// Mean + self row go to LDS only for the cross-lane matmul.
__global__ __launch_bounds__(256) void sage_layer(
    const float* __restrict__ hin, const int* __restrict__ row_ptr,
    const int* __restrict__ cnt, const int* __restrict__ csr_src,
    const float* __restrict__ inv,
    const float* __restrict__ Wl, const float* __restrict__ Wr,
    const float* __restrict__ bvec, float* __restrict__ out, int relu)
{
    __shared__ float WlT[D * D];
    __shared__ float WrT[D * D];
    __shared__ float bias[D];
    __shared__ float smean[4][D];
    __shared__ float sh[4][D];

    int t = threadIdx.x;
    for (int i = t; i < D * D; i += 256) {
        int o = i >> 6, k = i & 63;
        WlT[k * D + o] = Wl[i];
        WrT[k * D + o] = Wr[i];
    }
    if (t < D) bias[t] = bvec[t];
    __syncthreads();

    int nl = t >> 6;   // wave id
    int o  = t & 63;   // lane = channel

    for (int base = blockIdx.x * 4; base < N_NODES; base += gridDim.x * 4) {
        int node = base + nl;
        float acc = 0.f, hv = 0.f;
        if (node < N_NODES) {
            int s0 = row_ptr[node];
            int c  = cnt[node];
            int j = 0;
            for (; j + 4 <= c; j += 4) {   // 4-deep MLP on the row gathers
                int i0 = csr_src[s0 + j];
                int i1 = csr_src[s0 + j + 1];
                int i2 = csr_src[s0 + j + 2];
                int i3 = csr_src[s0 + j + 3];
                acc += hin[(long long)i0 * D + o];
                acc += hin[(long long)i1 * D + o];
                acc += hin[(long long)i2 * D + o];
                acc += hin[(long long)i3 * D + o];
            }
            for (; j < c; ++j) acc += hin[(long long)csr_src[s0 + j] * D + o];
            acc *= inv[node];
            hv = hin[(long long)node * D + o];
        }
        smean[nl][o] = acc;
        sh[nl][o]    = hv;
        __syncthreads();
        if (node < N_NODES) {
            float a2 = bias[o];
            #pragma unroll
            for (int k = 0; k < D; ++k) {
                a2 += smean[nl][k] * WlT[k * D + o] + sh[nl][k] * WrT[k * D + o];
            }
            if (relu) a2 = fmaxf(a2, 0.f);
            out[(long long)node * D + o] = a2;
        }
        __syncthreads();
    }
}

extern "C" void kernel_launch(void* const* d_in, const int* in_sizes, int n_in,
                              void* d_out, int out_size, void* d_ws, size_t ws_size,
                              hipStream_t stream) {
    const float* x   = (const float*)d_in[0];
    const int*   ei  = (const int*)d_in[1];
    const int*   src = ei;
    const int*   dst = ei + N_EDGES;
    const float* Wl0 = (const float*)d_in[2];
    const float* Wr0 = (const float*)d_in[3];
    const float* b0  = (const float*)d_in[4];
    const float* Wl1 = (const float*)d_in[5];
    const float* Wr1 = (const float*)d_in[6];
    const float* b1  = (const float*)d_in[7];
    const float* Wl2 = (const float*)d_in[8];
    const float* Wr2 = (const float*)d_in[9];
    const float* b2  = (const float*)d_in[10];
    float* out = (float*)d_out;

    int*   cnt     = (int*)d_ws;                       // N
    int*   row_ptr = cnt + N_NODES;                    // N
    int*   cur     = row_ptr + N_NODES;                // N
    int*   csr_src = cur + N_NODES;                    // E
    float* inv     = (float*)(csr_src + N_EDGES);      // N
    float* h0      = inv + N_NODES;                    // N*D
    float* h1      = h0 + (size_t)N_NODES * D;         // N*D

    const int BLK = 256;
    const int edge_grid = (N_EDGES + BLK - 1) / BLK;
    const int node_grid = (N_NODES + BLK - 1) / BLK;
    const int scan_grid = (N_NODES + SCAN_BLK - 1) / SCAN_BLK;
    const int layer_grid = 1024;   // 4 blocks/CU (LDS-limited), grid-stride

    // ---- CSR build (once per call; graph is layer-invariant) ----
    hipMemsetAsync(cnt, 0, (size_t)N_NODES * sizeof(int), stream);
    hipMemsetAsync(cur, 0, (size_t)N_NODES * sizeof(int), stream);
    count_kernel<<<edge_grid, BLK, 0, stream>>>(dst, cnt);
    scan_kernel<<<scan_grid, SCAN_BLK, 0, stream>>>(cnt, row_ptr);
    inv_kernel<<<node_grid, BLK, 0, stream>>>(cnt, inv);
    fill_kernel<<<edge_grid, BLK, 0, stream>>>(src, dst, row_ptr, cur, csr_src);

    // ---- 3 fused layers ----
    sage_layer<<<layer_grid, BLK, 0, stream>>>(x,  row_ptr, cnt, csr_src, inv, Wl0, Wr0, b0, h0, 1);
    sage_layer<<<layer_grid, BLK, 0, stream>>>(h0, row_ptr, cnt, csr_src, inv, Wl1, Wr1, b1, h1, 1);
    sage_layer<<<layer_grid, BLK, 0, stream>>>(h1, row_ptr, cnt, csr_src, inv, Wl2, Wr2, b2, out, 0);
}

// Round 3
// 498.294 us; speedup vs baseline: 10.4494x; 1.3205x over previous
//
#include <hip/hip_runtime.h>

#define N_NODES 100000
#define N_EDGES 1600000
#define D 64
#define SCAN_BLK 1024
#define LBLK 512

typedef unsigned int u32;
typedef unsigned short u16;

__device__ __forceinline__ u16 f32_to_bf16(float f) {
    u32 u = __float_as_uint(f);
    u32 r = u + 0x7fffu + ((u >> 16) & 1u);
    return (u16)(r >> 16);
}
__device__ __forceinline__ float bf16lo_to_f32(u32 packed) {
    return __uint_as_float(packed << 16);
}
__device__ __forceinline__ float bf16hi_to_f32(u32 packed) {
    return __uint_as_float(packed & 0xffff0000u);
}

// ---------------- degree count (int atomics) ----------------
__global__ void count_kernel(const int* __restrict__ dst, int* __restrict__ cnt) {
    int e = blockIdx.x * blockDim.x + threadIdx.x;
    if (e < N_EDGES) atomicAdd(&cnt[dst[e]], 1);
}

// ---------------- exclusive scan of cnt -> row_ptr ----------------
__global__ __launch_bounds__(SCAN_BLK) void scan_kernel(const int* __restrict__ cnt,
                                                        int* __restrict__ row_ptr) {
    __shared__ int s[SCAN_BLK];
    __shared__ int red[SCAN_BLK / 64];
    int t = threadIdx.x;
    long long blockStart = (long long)blockIdx.x * SCAN_BLK;

    int partial = 0;
    for (long long i = t; i < blockStart; i += SCAN_BLK) partial += cnt[i];
    for (int off = 32; off > 0; off >>= 1) partial += __shfl_down(partial, off, 64);
    if ((t & 63) == 0) red[t >> 6] = partial;
    __syncthreads();
    if (t == 0) {
        int a = 0;
        for (int w = 0; w < SCAN_BLK / 64; ++w) a += red[w];
        red[0] = a;
    }
    __syncthreads();
    int offset = red[0];

    int idx = (int)blockStart + t;
    int v = (idx < N_NODES) ? cnt[idx] : 0;
    s[t] = v;
    __syncthreads();
    for (int off = 1; off < SCAN_BLK; off <<= 1) {
        int a = (t >= off) ? s[t - off] : 0;
        __syncthreads();
        s[t] += a;
        __syncthreads();
    }
    if (idx < N_NODES) row_ptr[idx] = offset + s[t] - v;  // exclusive
}

// ---------------- CSR bucket fill ----------------
__global__ void fill_kernel(const int* __restrict__ src, const int* __restrict__ dst,
                            const int* __restrict__ row_ptr, int* __restrict__ cur,
                            int* __restrict__ csr_src) {
    int e = blockIdx.x * blockDim.x + threadIdx.x;
    if (e < N_EDGES) {
        int d = dst[e];
        int pos = row_ptr[d] + atomicAdd(&cur[d], 1);
        csr_src[pos] = src[e];
    }
}

__global__ void inv_kernel(const int* __restrict__ cnt, float* __restrict__ inv) {
    int n = blockIdx.x * blockDim.x + threadIdx.x;
    if (n < N_NODES) inv[n] = 1.0f / fmaxf((float)cnt[n], 1.0f);
}

// ---------------- f32 -> bf16 conversion (4 elems/thread) ----------------
__global__ void tobf16_kernel(const float* __restrict__ in, u16* __restrict__ outb, int n4) {
    int i = blockIdx.x * blockDim.x + threadIdx.x;
    if (i < n4) {
        float4 v = reinterpret_cast<const float4*>(in)[i];
        uint2 p;
        p.x = (u32)f32_to_bf16(v.x) | ((u32)f32_to_bf16(v.y) << 16);
        p.y = (u32)f32_to_bf16(v.z) | ((u32)f32_to_bf16(v.w) << 16);
        reinterpret_cast<uint2*>(outb)[i] = p;
    }
}

// ---------------- fused SAGE layer ----------------
// 512 threads = 8 waves; wave w = one node per iteration, grid-stride by 8*grid.
// Gather: bf16 rows; lane split sub=lane>>4 (edge in quad), cg=lane&15 (channel quad).
// One 8B load = 4 channels of 1 edge; wave covers 4 edges/step, unrolled x2 -> 8 in flight.
// Subgroup partial sums reduced with __shfl_xor(16),(32).
// Matmul: weights staged transposed in LDS with stride-65 padding (conflict-free
// both on staging writes and on lane-consecutive reads).
__global__ __launch_bounds__(LBLK, 8) void sage_layer(
    const u16* __restrict__ hb,      // bf16 gather source [N][D]
    const float* __restrict__ hf,    // f32 self source (nullptr -> use hb)
    const int* __restrict__ row_ptr, const int* __restrict__ cnt,
    const int* __restrict__ csr_src, const float* __restrict__ inv,
    const float* __restrict__ Wl, const float* __restrict__ Wr,
    const float* __restrict__ bvec,
    float* __restrict__ outf,        // f32 output (nullptr to skip)
    u16* __restrict__ outb,          // bf16 output (nullptr to skip)
    int relu)
{
    __shared__ float WlT[D * 65];
    __shared__ float WrT[D * 65];
    __shared__ float bias[D];
    __shared__ float smean[8][D];
    __shared__ float sh[8][D];

    int t = threadIdx.x;
    for (int i = t; i < D * D; i += LBLK) {
        int o = i >> 6, k = i & 63;
        WlT[k * 65 + o] = Wl[i];
        WrT[k * 65 + o] = Wr[i];
    }
    if (t < D) bias[t] = bvec[t];
    __syncthreads();

    int w    = t >> 6;      // wave id 0..7
    int lane = t & 63;
    int cg4  = (lane & 15) * 4;  // channel offset
    int sub  = lane >> 4;        // edge subgroup 0..3

    for (int base = blockIdx.x * 8; base < N_NODES; base += gridDim.x * 8) {
        int node = base + w;
        float4 acc = make_float4(0.f, 0.f, 0.f, 0.f);
        if (node < N_NODES) {
            int s0 = row_ptr[node];
            int c  = cnt[node];
            int j = 0;
            for (; j + 8 <= c; j += 8) {
                int i0 = csr_src[s0 + j + sub];
                int i1 = csr_src[s0 + j + 4 + sub];
                uint2 v0 = *reinterpret_cast<const uint2*>(&hb[i0 * D + cg4]);
                uint2 v1 = *reinterpret_cast<const uint2*>(&hb[i1 * D + cg4]);
                acc.x += bf16lo_to_f32(v0.x); acc.y += bf16hi_to_f32(v0.x);
                acc.z += bf16lo_to_f32(v0.y); acc.w += bf16hi_to_f32(v0.y);
                acc.x += bf16lo_to_f32(v1.x); acc.y += bf16hi_to_f32(v1.x);
                acc.z += bf16lo_to_f32(v1.y); acc.w += bf16hi_to_f32(v1.y);
            }
            for (; j < c; j += 4) {
                int jj = j + sub;
                if (jj < c) {
                    int i0 = csr_src[s0 + jj];
                    uint2 v0 = *reinterpret_cast<const uint2*>(&hb[i0 * D + cg4]);
                    acc.x += bf16lo_to_f32(v0.x); acc.y += bf16hi_to_f32(v0.x);
                    acc.z += bf16lo_to_f32(v0.y); acc.w += bf16hi_to_f32(v0.y);
                }
            }
        }
        // reduce the 4 edge-subgroups (lanes l, l+16, l+32, l+48)
        acc.x += __shfl_xor(acc.x, 16); acc.y += __shfl_xor(acc.y, 16);
        acc.z += __shfl_xor(acc.z, 16); acc.w += __shfl_xor(acc.w, 16);
        acc.x += __shfl_xor(acc.x, 32); acc.y += __shfl_xor(acc.y, 32);
        acc.z += __shfl_xor(acc.z, 32); acc.w += __shfl_xor(acc.w, 32);

        if (node < N_NODES) {
            float s = inv[node];
            if (sub == 0) {
                float4 m = make_float4(acc.x * s, acc.y * s, acc.z * s, acc.w * s);
                *reinterpret_cast<float4*>(&smean[w][cg4]) = m;
            }
            float hv = hf ? hf[node * D + lane]
                          : __uint_as_float(((u32)hb[node * D + lane]) << 16);
            sh[w][lane] = hv;
        }
        __syncthreads();
        if (node < N_NODES) {
            float a2 = bias[lane];
            #pragma unroll
            for (int k = 0; k < D; ++k) {
                a2 += smean[w][k] * WlT[k * 65 + lane] + sh[w][k] * WrT[k * 65 + lane];
            }
            if (relu) a2 = fmaxf(a2, 0.f);
            if (outf) outf[node * D + lane] = a2;
            if (outb) outb[node * D + lane] = f32_to_bf16(a2);
        }
        __syncthreads();
    }
}

extern "C" void kernel_launch(void* const* d_in, const int* in_sizes, int n_in,
                              void* d_out, int out_size, void* d_ws, size_t ws_size,
                              hipStream_t stream) {
    const float* x   = (const float*)d_in[0];
    const int*   ei  = (const int*)d_in[1];
    const int*   src = ei;
    const int*   dst = ei + N_EDGES;
    const float* Wl0 = (const float*)d_in[2];
    const float* Wr0 = (const float*)d_in[3];
    const float* b0  = (const float*)d_in[4];
    const float* Wl1 = (const float*)d_in[5];
    const float* Wr1 = (const float*)d_in[6];
    const float* b1  = (const float*)d_in[7];
    const float* Wl2 = (const float*)d_in[8];
    const float* Wr2 = (const float*)d_in[9];
    const float* b2  = (const float*)d_in[10];
    float* out = (float*)d_out;

    // ---- workspace layout (all regions 256B-aligned) ----
    char* p = (char*)d_ws;
    auto take = [&](size_t bytes) { char* r = p; p += (bytes + 255) & ~(size_t)255; return r; };
    int*   cnt     = (int*)take((size_t)N_NODES * 4);
    int*   row_ptr = (int*)take((size_t)N_NODES * 4);
    int*   cur     = (int*)take((size_t)N_NODES * 4);
    int*   csr_src = (int*)take((size_t)N_EDGES * 4);
    float* inv     = (float*)take((size_t)N_NODES * 4);
    u16*   xb      = (u16*)take((size_t)N_NODES * D * 2);
    u16*   h0b     = (u16*)take((size_t)N_NODES * D * 2);
    u16*   h1b     = (u16*)take((size_t)N_NODES * D * 2);
    size_t lean_bytes = (size_t)(p - (char*)d_ws);
    size_t full_bytes = lean_bytes + 2 * (((size_t)N_NODES * D * 4 + 255) & ~(size_t)255);
    bool full = ws_size >= full_bytes;
    float* h0f = nullptr;
    float* h1f = nullptr;
    if (full) {
        h0f = (float*)take((size_t)N_NODES * D * 4);
        h1f = (float*)take((size_t)N_NODES * D * 4);
    }

    const int BLK = 256;
    const int edge_grid  = (N_EDGES + BLK - 1) / BLK;
    const int node_grid  = (N_NODES + BLK - 1) / BLK;
    const int scan_grid  = (N_NODES + SCAN_BLK - 1) / SCAN_BLK;
    const int conv_grid  = (N_NODES * D / 4 + BLK - 1) / BLK;
    const int layer_grid = 1024;   // 4 blocks/CU, grid-stride over node-groups

    // ---- CSR build (graph is layer-invariant; once per call) ----
    hipMemsetAsync(cnt, 0, (size_t)N_NODES * sizeof(int), stream);
    hipMemsetAsync(cur, 0, (size_t)N_NODES * sizeof(int), stream);
    count_kernel<<<edge_grid, BLK, 0, stream>>>(dst, cnt);
    scan_kernel<<<scan_grid, SCAN_BLK, 0, stream>>>(cnt, row_ptr);
    inv_kernel<<<node_grid, BLK, 0, stream>>>(cnt, inv);
    fill_kernel<<<edge_grid, BLK, 0, stream>>>(src, dst, row_ptr, cur, csr_src);
    tobf16_kernel<<<conv_grid, BLK, 0, stream>>>(x, xb, N_NODES * D / 4);

    // ---- 3 fused layers ----
    if (full) {
        sage_layer<<<layer_grid, LBLK, 0, stream>>>(xb,  x,   row_ptr, cnt, csr_src, inv, Wl0, Wr0, b0, h0f, h0b, 1);
        sage_layer<<<layer_grid, LBLK, 0, stream>>>(h0b, h0f, row_ptr, cnt, csr_src, inv, Wl1, Wr1, b1, h1f, h1b, 1);
        sage_layer<<<layer_grid, LBLK, 0, stream>>>(h1b, h1f, row_ptr, cnt, csr_src, inv, Wl2, Wr2, b2, out, nullptr, 0);
    } else {
        sage_layer<<<layer_grid, LBLK, 0, stream>>>(xb,  x,      row_ptr, cnt, csr_src, inv, Wl0, Wr0, b0, nullptr, h0b, 1);
        sage_layer<<<layer_grid, LBLK, 0, stream>>>(h0b, nullptr, row_ptr, cnt, csr_src, inv, Wl1, Wr1, b1, nullptr, h1b, 1);
        sage_layer<<<layer_grid, LBLK, 0, stream>>>(h1b, nullptr, row_ptr, cnt, csr_src, inv, Wl2, Wr2, b2, out, nullptr, 0);
    }
}

// Round 4
// 451.540 us; speedup vs baseline: 11.5313x; 1.1035x over previous
//
#include <hip/hip_runtime.h>

#define N_NODES 100000
#define N_EDGES 1600000
#define D 64
#define SCAN_BLK 1024

typedef unsigned int u32;
typedef unsigned short u16;
typedef _Float16 f16;
typedef f16 f16x8 __attribute__((ext_vector_type(8)));
typedef float f32x4 __attribute__((ext_vector_type(4)));

// ---------------- degree count (int atomics) ----------------
__global__ void count_kernel(const int* __restrict__ dst, int* __restrict__ cnt) {
    int e = blockIdx.x * blockDim.x + threadIdx.x;
    if (e < N_EDGES) atomicAdd(&cnt[dst[e]], 1);
}

// ---------------- exclusive scan of cnt -> row_ptr ----------------
__global__ __launch_bounds__(SCAN_BLK) void scan_kernel(const int* __restrict__ cnt,
                                                        int* __restrict__ row_ptr) {
    __shared__ int s[SCAN_BLK];
    __shared__ int red[SCAN_BLK / 64];
    int t = threadIdx.x;
    long long blockStart = (long long)blockIdx.x * SCAN_BLK;

    int partial = 0;
    for (long long i = t; i < blockStart; i += SCAN_BLK) partial += cnt[i];
    for (int off = 32; off > 0; off >>= 1) partial += __shfl_down(partial, off, 64);
    if ((t & 63) == 0) red[t >> 6] = partial;
    __syncthreads();
    if (t == 0) {
        int a = 0;
        for (int w = 0; w < SCAN_BLK / 64; ++w) a += red[w];
        red[0] = a;
    }
    __syncthreads();
    int offset = red[0];

    int idx = (int)blockStart + t;
    int v = (idx < N_NODES) ? cnt[idx] : 0;
    s[t] = v;
    __syncthreads();
    for (int off = 1; off < SCAN_BLK; off <<= 1) {
        int a = (t >= off) ? s[t - off] : 0;
        __syncthreads();
        s[t] += a;
        __syncthreads();
    }
    if (idx < N_NODES) row_ptr[idx] = offset + s[t] - v;  // exclusive
}

// ---------------- CSR bucket fill ----------------
__global__ void fill_kernel(const int* __restrict__ src, const int* __restrict__ dst,
                            const int* __restrict__ row_ptr, int* __restrict__ cur,
                            int* __restrict__ csr_src) {
    int e = blockIdx.x * blockDim.x + threadIdx.x;
    if (e < N_EDGES) {
        int d = dst[e];
        int pos = row_ptr[d] + atomicAdd(&cur[d], 1);
        csr_src[pos] = src[e];
    }
}

__global__ void inv_kernel(const int* __restrict__ cnt, float* __restrict__ inv) {
    int n = blockIdx.x * blockDim.x + threadIdx.x;
    if (n < N_NODES) inv[n] = 1.0f / fmaxf((float)cnt[n], 1.0f);
}

// ---------------- f32 -> f16 conversion (4 elems/thread) ----------------
__global__ void tof16_kernel(const float* __restrict__ in, u16* __restrict__ outh, int n4) {
    int i = blockIdx.x * blockDim.x + threadIdx.x;
    if (i < n4) {
        float4 v = reinterpret_cast<const float4*>(in)[i];
        union { f16 h[4]; uint2 u; } cv;
        cv.h[0] = (f16)v.x; cv.h[1] = (f16)v.y; cv.h[2] = (f16)v.z; cv.h[3] = (f16)v.w;
        reinterpret_cast<uint2*>(outh)[i] = cv.u;
    }
}

__device__ __forceinline__ void add8(float* va, uint4 r) {
    union { uint4 u; f16x8 h; } cv; cv.u = r;
    #pragma unroll
    for (int e = 0; e < 8; ++e) va[e] += (float)cv.h[e];
}

// ---------------- fused SAGE layer (MFMA) ----------------
// 256 threads = 4 waves; wave w owns 16 nodes (base = blk*64 + w*16).
// Gather: 8 lanes/row (uint4 = 8 f16 channels), sub = lane>>3 edge subgroup,
// 16 edges per unrolled iter; butterfly shfl_xor(8,16,32) reduce.
// A-tile per wave [16 nodes][128 k] f16 (k<64 mean, k>=64 self), 16B-chunk
// XOR-swizzled by node row -> conflict-free frag reads (ds_read_b128).
// B = [WlT; WrT] pre-arranged once per block into 16 MFMA fragments in LDS.
// 16x mfma_f32_16x16x32_f16 per 16 nodes. No block barriers in the loop.
__global__ __launch_bounds__(256, 4) void sage_layer(
    const u16* __restrict__ hh,        // f16 features [N][64]
    const int* __restrict__ row_ptr, const int* __restrict__ cnt,
    const int* __restrict__ csr_src, const float* __restrict__ inv,
    const float* __restrict__ Wl, const float* __restrict__ Wr,
    const float* __restrict__ bvec,
    float* __restrict__ outf,          // f32 output (nullptr to skip)
    u16* __restrict__ outh,            // f16 output (nullptr to skip)
    int relu)
{
    __shared__ uint4 Blds[16 * 64];        // 16 fragments x 64 lanes x 16B
    __shared__ u16 Atile[4][16][128];      // per-wave swizzled A

    int t = threadIdx.x;

    // ---- arrange B fragments: frag f=(ktg*4+nt): lane l elem e = W[o=nt*16+(l&15)][k]
    for (int idx = t; idx < 16 * 64; idx += 256) {
        int f = idx >> 6, l = idx & 63;
        int ktg = f >> 2, nt = f & 3;
        const float* W = (ktg & 2) ? Wr : Wl;
        int o = nt * 16 + (l & 15);
        int k = (ktg & 1) * 32 + (l >> 4) * 8;
        const float* s = W + o * 64 + k;
        float4 v0 = *reinterpret_cast<const float4*>(s);
        float4 v1 = *reinterpret_cast<const float4*>(s + 4);
        union { f16x8 h; uint4 u; } cv;
        cv.h[0] = (f16)v0.x; cv.h[1] = (f16)v0.y; cv.h[2] = (f16)v0.z; cv.h[3] = (f16)v0.w;
        cv.h[4] = (f16)v1.x; cv.h[5] = (f16)v1.y; cv.h[6] = (f16)v1.z; cv.h[7] = (f16)v1.w;
        Blds[idx] = cv.u;
    }
    __syncthreads();

    int w    = t >> 6;
    int lane = t & 63;
    int j8   = lane & 7;    // channel octet within row / row-lane
    int sub  = lane >> 3;   // edge subgroup 0..7
    const uint4* rows = reinterpret_cast<const uint4*>(hh);   // 8 x uint4 per node

    int base = blockIdx.x * 64 + w * 16;

    float bias[4];
    #pragma unroll
    for (int nt = 0; nt < 4; ++nt) bias[nt] = bvec[nt * 16 + (lane & 15)];

    // ---- gather 16 nodes into A-tile ----
    for (int n = 0; n < 16; ++n) {
        int node = base + n;
        if (node >= N_NODES) break;             // wave-uniform
        uint4 selfrow = rows[node * 8 + j8];    // in flight during gather
        int s0 = row_ptr[node];
        int c  = cnt[node];
        float va[8] = {0.f,0.f,0.f,0.f,0.f,0.f,0.f,0.f};
        int j = 0;
        for (; j + 16 <= c; j += 16) {
            int i0 = csr_src[s0 + j + sub];
            int i1 = csr_src[s0 + j + 8 + sub];
            uint4 r0 = rows[i0 * 8 + j8];
            uint4 r1 = rows[i1 * 8 + j8];
            add8(va, r0);
            add8(va, r1);
        }
        for (; j + 8 <= c; j += 8) {
            int i0 = csr_src[s0 + j + sub];
            uint4 r0 = rows[i0 * 8 + j8];
            add8(va, r0);
        }
        int rem = c - j;
        if (sub < rem) {
            int i0 = csr_src[s0 + j + sub];
            uint4 r0 = rows[i0 * 8 + j8];
            add8(va, r0);
        }
        // butterfly reduce over the 8 edge-subgroups
        #pragma unroll
        for (int e = 0; e < 8; ++e) {
            va[e] += __shfl_xor(va[e], 8);
            va[e] += __shfl_xor(va[e], 16);
            va[e] += __shfl_xor(va[e], 32);
        }
        int chunk = j8 ^ (n & 7);
        if (lane < 8) {                 // mean -> k 0..63
            float sc = inv[node];
            union { f16x8 h; uint4 u; } cv;
            #pragma unroll
            for (int e = 0; e < 8; ++e) cv.h[e] = (f16)(va[e] * sc);
            *reinterpret_cast<uint4*>(&Atile[w][n][chunk * 8]) = cv.u;
        } else if (lane < 16) {         // self -> k 64..127
            *reinterpret_cast<uint4*>(&Atile[w][n][64 + chunk * 8]) = selfrow;
        }
    }

    // ---- fragment reads + 16 MFMAs ----
    f32x4 acc[4] = {};
    int row = lane & 15, kg = lane >> 4;
    #pragma unroll
    for (int ktg = 0; ktg < 4; ++ktg) {
        int idx16 = ktg * 4 + kg;
        int swz = (idx16 & 8) | ((idx16 & 7) ^ (row & 7));
        uint4 a = *reinterpret_cast<const uint4*>(&Atile[w][row][swz * 8]);
        union { uint4 u; f16x8 h; } av; av.u = a;
        #pragma unroll
        for (int nt = 0; nt < 4; ++nt) {
            union { uint4 u; f16x8 h; } bv; bv.u = Blds[(ktg * 4 + nt) * 64 + lane];
            acc[nt] = __builtin_amdgcn_mfma_f32_16x16x32_f16(av.h, bv.h, acc[nt], 0, 0, 0);
        }
    }

    // ---- epilogue: bias (+ReLU), stores. C: col=lane&15, row=(lane>>4)*4+reg ----
    #pragma unroll
    for (int nt = 0; nt < 4; ++nt) {
        int o = nt * 16 + (lane & 15);
        #pragma unroll
        for (int r = 0; r < 4; ++r) {
            int n = kg * 4 + r;
            int node = base + n;
            if (node < N_NODES) {
                float vout = acc[nt][r] + bias[nt];
                if (relu) vout = fmaxf(vout, 0.f);
                if (outf) outf[node * 64 + o] = vout;
                if (outh) {
                    union { f16 h; u16 u; } cv; cv.h = (f16)vout;
                    outh[node * 64 + o] = cv.u;
                }
            }
        }
    }
}

extern "C" void kernel_launch(void* const* d_in, const int* in_sizes, int n_in,
                              void* d_out, int out_size, void* d_ws, size_t ws_size,
                              hipStream_t stream) {
    const float* x   = (const float*)d_in[0];
    const int*   ei  = (const int*)d_in[1];
    const int*   src = ei;
    const int*   dst = ei + N_EDGES;
    const float* Wl0 = (const float*)d_in[2];
    const float* Wr0 = (const float*)d_in[3];
    const float* b0  = (const float*)d_in[4];
    const float* Wl1 = (const float*)d_in[5];
    const float* Wr1 = (const float*)d_in[6];
    const float* b1  = (const float*)d_in[7];
    const float* Wl2 = (const float*)d_in[8];
    const float* Wr2 = (const float*)d_in[9];
    const float* b2  = (const float*)d_in[10];
    float* out = (float*)d_out;

    // ---- workspace layout (256B-aligned regions) ----
    char* p = (char*)d_ws;
    auto take = [&](size_t bytes) { char* r = p; p += (bytes + 255) & ~(size_t)255; return r; };
    int*   cnt     = (int*)take((size_t)N_NODES * 4);
    int*   row_ptr = (int*)take((size_t)N_NODES * 4);
    int*   cur     = (int*)take((size_t)N_NODES * 4);
    int*   csr_src = (int*)take((size_t)N_EDGES * 4);
    float* inv     = (float*)take((size_t)N_NODES * 4);
    u16*   xh      = (u16*)take((size_t)N_NODES * D * 2);
    u16*   h0h     = (u16*)take((size_t)N_NODES * D * 2);
    u16*   h1h     = (u16*)take((size_t)N_NODES * D * 2);

    const int BLK = 256;
    const int edge_grid  = (N_EDGES + BLK - 1) / BLK;
    const int node_grid  = (N_NODES + BLK - 1) / BLK;
    const int scan_grid  = (N_NODES + SCAN_BLK - 1) / SCAN_BLK;
    const int conv_grid  = (N_NODES * D / 4 + BLK - 1) / BLK;
    const int layer_grid = (N_NODES + 63) / 64;    // 64 nodes per block

    // ---- CSR build (graph is layer-invariant; once per call) ----
    hipMemsetAsync(cnt, 0, (size_t)N_NODES * sizeof(int), stream);
    hipMemsetAsync(cur, 0, (size_t)N_NODES * sizeof(int), stream);
    count_kernel<<<edge_grid, BLK, 0, stream>>>(dst, cnt);
    scan_kernel<<<scan_grid, SCAN_BLK, 0, stream>>>(cnt, row_ptr);
    inv_kernel<<<node_grid, BLK, 0, stream>>>(cnt, inv);
    fill_kernel<<<edge_grid, BLK, 0, stream>>>(src, dst, row_ptr, cur, csr_src);
    tof16_kernel<<<conv_grid, BLK, 0, stream>>>(x, xh, N_NODES * D / 4);

    // ---- 3 fused layers (intermediates are f16-only) ----
    sage_layer<<<layer_grid, BLK, 0, stream>>>(xh,  row_ptr, cnt, csr_src, inv, Wl0, Wr0, b0, nullptr, h0h, 1);
    sage_layer<<<layer_grid, BLK, 0, stream>>>(h0h, row_ptr, cnt, csr_src, inv, Wl1, Wr1, b1, nullptr, h1h, 1);
    sage_layer<<<layer_grid, BLK, 0, stream>>>(h1h, row_ptr, cnt, csr_src, inv, Wl2, Wr2, b2, out, nullptr, 0);
}